// Round 1
// baseline (60.066 us; speedup 1.0000x reference)
//
#include <hip/hip_runtime.h>

#define NSLICE 6
#define NPIX   4096
#define M      20             // Fourier frequencies 1..M
#define NWAVE  16             // 1024 threads = 16 waves

// K(d) = exp(-(d/sigma)^2), sigma=0.1, on d in [-1,1]:
//   K(d) ~= c0 + sum_{m=1..M} 2*c_m*cos(pi*m*d),
//   c_m = (sigma*sqrt(pi)/2)*exp(-(pi*m*sigma)^2/4)
#define C0         0.088622693f    // sigma*sqrt(pi)/2
#define TWO_C0     0.177245385f
#define AEXP_LOG2  0.035597112f    // (pi*sigma)^2/4 * log2(e)
#define DEN0       362.99854f      // C0 * NPIX

// ---------------------------------------------------------------------------
// Fully fused: one block per slice, 1024 threads (16 waves).
//   stage:   one float4/thread -> LDS (kept in regs for phase 2) + block sum X
//   phase 1: wave w -> frequency m=w+1 (and m=w+17 for w<4). Direct
//            sin(pi*m*v) via v_sin on revolutions. Wave-reduce 4 moments,
//            lane 0 writes coef-scaled F entry to LDS. No ws round-trip.
//   phase 2: Chebyshev recurrence per pixel; F[m] read ONCE per m as a
//            broadcast ds_read_b128 shared across the thread's 4 pixels.
// Removes the second dispatch + K1->K2 stream serialization entirely.
__global__ __launch_bounds__(1024) void bilateral_fused(
        const float* __restrict__ x, float* __restrict__ out) {
    const int s    = blockIdx.x;
    const int tid  = threadIdx.x;
    const int wid  = tid >> 6;
    const int lane = tid & 63;

    __shared__ __align__(16) float xs[NPIX];            // 16 KB slice stage
    __shared__ __align__(16) float fin[(M + 1) * 4];    // F table
    __shared__ float red[NWAVE];

    // One coalesced float4 per thread; lives in registers through phase 1.
    const float4 v4 = ((const float4*)(x + s * NPIX))[tid];
    ((float4*)xs)[tid] = v4;

    // Block sum of v for the m=0 numerator term (rides the staging sync).
    float xsum = (v4.x + v4.y) + (v4.z + v4.w);
    #pragma unroll
    for (int off = 1; off < 64; off <<= 1) xsum += __shfl_xor(xsum, off);
    if (lane == 0) red[wid] = xsum;
    __syncthreads();

    if (tid == 0) {
        float X = 0.f;
        #pragma unroll
        for (int w = 0; w < NWAVE; ++w) X += red[w];
        fin[0] = DEN0; fin[1] = C0 * X; fin[2] = 0.f; fin[3] = 0.f;
    }

    // ---- phase 1: moments. 20 freqs over 16 waves -> 5 freqs per SIMD. ----
    for (int m = wid + 1; m <= M; m += NWAVE) {
        const float fm = (float)m;
        float Sc = 0.f, Ss = 0.f, Tc = 0.f, Ts = 0.f;
        #pragma unroll 8
        for (int i = 0; i < NPIX / 128; ++i) {          // 32 iters, 2 px/lane
            float p0 = xs[i * 128 + lane];              // stride-1: conflict-free
            float p1 = xs[i * 128 + 64 + lane];
            float a0 = 0.5f * fm * p0;                  // revolutions
            float a1 = 0.5f * fm * p1;
            float sn0 = __builtin_amdgcn_sinf(a0), cn0 = __builtin_amdgcn_cosf(a0);
            float sn1 = __builtin_amdgcn_sinf(a1), cn1 = __builtin_amdgcn_cosf(a1);
            Sc += cn0 + cn1;  Ss += sn0 + sn1;
            Tc = fmaf(p0, cn0, Tc);  Tc = fmaf(p1, cn1, Tc);
            Ts = fmaf(p0, sn0, Ts);  Ts = fmaf(p1, sn1, Ts);
        }
        #pragma unroll
        for (int off = 1; off < 64; off <<= 1) {
            Sc += __shfl_xor(Sc, off);  Ss += __shfl_xor(Ss, off);
            Tc += __shfl_xor(Tc, off);  Ts += __shfl_xor(Ts, off);
        }
        if (lane == 0) {
            float coef = TWO_C0 * __builtin_amdgcn_exp2f(-AEXP_LOG2 * fm * fm);
            float* f = fin + m * 4;
            f[0] = coef * Sc;  f[1] = coef * Ss;
            f[2] = coef * Tc;  f[3] = coef * Ts;
        }
    }
    __syncthreads();

    // ---- phase 2: recombine 4 px/thread, F[m] broadcast once per m. ----
    const float4* F = (const float4*)fin;
    const float vv[4] = {v4.x, v4.y, v4.z, v4.w};
    float c1[4], s1[4], t2[4], cm1[4], cm2[4], sm1[4], sm2[4], den[4], num[4];
    const float4 f0 = F[0], f1 = F[1];
    #pragma unroll
    for (int j = 0; j < 4; ++j) {
        s1[j] = __builtin_amdgcn_sinf(0.5f * vv[j]);    // sin(pi*v)
        c1[j] = __builtin_amdgcn_cosf(0.5f * vv[j]);    // cos(pi*v)
        den[j] = fmaf(c1[j], f1.x, f0.x);  den[j] = fmaf(s1[j], f1.y, den[j]);
        num[j] = fmaf(c1[j], f1.z, f0.y);  num[j] = fmaf(s1[j], f1.w, num[j]);
        t2[j]  = c1[j] + c1[j];
        cm2[j] = 1.f;  sm2[j] = 0.f;  cm1[j] = c1[j];  sm1[j] = s1[j];
    }
    #pragma unroll
    for (int m2 = 2; m2 <= M; ++m2) {                   // Chebyshev in xp only
        const float4 f = F[m2];                          // ds_read_b128 broadcast
        #pragma unroll
        for (int j = 0; j < 4; ++j) {
            float cn = fmaf(t2[j], cm1[j], -cm2[j]);
            float sn = fmaf(t2[j], sm1[j], -sm2[j]);
            cm2[j] = cm1[j];  cm1[j] = cn;  sm2[j] = sm1[j];  sm1[j] = sn;
            den[j] = fmaf(cn, f.x, den[j]);  den[j] = fmaf(sn, f.y, den[j]);
            num[j] = fmaf(cn, f.z, num[j]);  num[j] = fmaf(sn, f.w, num[j]);
        }
    }
    float4 o;
    o.x = num[0] / den[0];  o.y = num[1] / den[1];
    o.z = num[2] / den[2];  o.w = num[3] / den[3];
    ((float4*)(out + s * NPIX))[tid] = o;
}

extern "C" void kernel_launch(void* const* d_in, const int* in_sizes, int n_in,
                              void* d_out, int out_size, void* d_ws, size_t ws_size,
                              hipStream_t stream) {
    (void)in_sizes; (void)n_in; (void)out_size; (void)d_ws; (void)ws_size;
    bilateral_fused<<<dim3(NSLICE), dim3(1024), 0, stream>>>(
        (const float*)d_in[0], (float*)d_out);
}

// Round 2
// 55.110 us; speedup vs baseline: 1.0899x; 1.0899x over previous
//
#include <hip/hip_runtime.h>

#define NSLICE 6
#define NPIX   4096
#define M      20             // Fourier frequencies 1..M

// K(d) = exp(-(d/sigma)^2), sigma=0.1, on d in [-1,1]:
//   K(d) ~= c0 + sum_{m=1..M} 2*c_m*cos(pi*m*d),
//   c_m = (sigma*sqrt(pi)/2)*exp(-(pi*m*sigma)^2/4)
// Tail at M=20 ~5e-6 abs; periodization ~exp(-100).
#define C0         0.088622693f    // sigma*sqrt(pi)/2
#define TWO_C0     0.177245385f
#define AEXP_LOG2  0.035597112f    // (pi*sigma)^2/4 * log2(e)
#define DEN0       362.99854f      // C0 * NPIX

// ---------------------------------------------------------------------------
// K1: one block per (frequency m, slice). 256 threads x 16 px. Only 5 live
// accumulators/thread -> no spill. sin(pi*m*v) = v_sin(0.5*m*v revolutions),
// computed directly per m — no recurrence, so frequencies parallelize across
// blocks (120 blocks -> 120 CUs; the round-1 fused variant on 6 CUs was
// +4.6 us slower: exec concentration costs more than the dispatch gap saves).
// ws layout: ws[(s*(M+1) + m)*4 + {0:Sc,1:Ss,2:Tc,3:Ts}], m=0 slot = const terms.
__global__ __launch_bounds__(256) void moments_kernel(
        const float* __restrict__ x, float* __restrict__ ws) {
    const int mi = blockIdx.x;           // 0..19 -> frequency mi+1
    const int s  = blockIdx.y;
    const float fm = (float)(mi + 1);
    const int tid = threadIdx.x;
    const float4* x4 = (const float4*)(x + s * NPIX);

    float Sc = 0.f, Ss = 0.f, Tc = 0.f, Ts = 0.f, X = 0.f;
    #pragma unroll
    for (int j = 0; j < NPIX / 4 / 256; ++j) {       // 4 iters, coalesced 16B
        float4 v4 = x4[j * 256 + tid];
        float vv[4] = {v4.x, v4.y, v4.z, v4.w};
        #pragma unroll
        for (int k = 0; k < 4; ++k) {
            float v   = vv[k];
            float arg = 0.5f * fm * v;               // revolutions
            float sn  = __builtin_amdgcn_sinf(arg);  // v_sin_f32
            float cn  = __builtin_amdgcn_cosf(arg);  // v_cos_f32
            Sc += cn;  Ss += sn;
            Tc = fmaf(v, cn, Tc);
            Ts = fmaf(v, sn, Ts);
            X += v;
        }
    }

    #pragma unroll
    for (int off = 1; off < 64; off <<= 1) {
        Sc += __shfl_xor(Sc, off);  Ss += __shfl_xor(Ss, off);
        Tc += __shfl_xor(Tc, off);  Ts += __shfl_xor(Ts, off);
        X  += __shfl_xor(X,  off);
    }
    __shared__ float red[4][5];
    const int w = tid >> 6;
    if ((tid & 63) == 0) {
        red[w][0] = Sc; red[w][1] = Ss; red[w][2] = Tc; red[w][3] = Ts; red[w][4] = X;
    }
    __syncthreads();
    if (tid == 0) {
        float sc = 0.f, ss = 0.f, tc = 0.f, ts = 0.f, xx = 0.f;
        #pragma unroll
        for (int ww = 0; ww < 4; ++ww) {
            sc += red[ww][0]; ss += red[ww][1]; tc += red[ww][2];
            ts += red[ww][3]; xx += red[ww][4];
        }
        float coef = TWO_C0 * __builtin_amdgcn_exp2f(-AEXP_LOG2 * fm * fm);
        float* f = ws + (s * (M + 1) + (mi + 1)) * 4;
        f[0] = coef * sc;  f[1] = coef * ss;
        f[2] = coef * tc;  f[3] = coef * ts;
        if (mi == 0) {                    // constant terms, written once/slice
            float* f0 = ws + s * (M + 1) * 4;
            f0[0] = DEN0;  f0[1] = C0 * xx;  f0[2] = 0.f;  f0[3] = 0.f;
        }
    }
}

// ---------------------------------------------------------------------------
// K2: one pixel per thread, 48 blocks x 512. F table staged in LDS and read
// per recurrence step (same-address broadcast, conflict-free). ~25 live VGPRs.
__global__ __launch_bounds__(512) void recombine_kernel(
        const float* __restrict__ x, const float* __restrict__ ws,
        float* __restrict__ out) {
    const int s = blockIdx.y;
    const int p = blockIdx.x * 512 + threadIdx.x;
    __shared__ __align__(16) float fin[(M + 1) * 4];
    if (threadIdx.x < (M + 1) * 4)
        fin[threadIdx.x] = ws[s * (M + 1) * 4 + threadIdx.x];
    __syncthreads();

    const float v  = x[s * NPIX + p];
    const float s1 = __builtin_amdgcn_sinf(0.5f * v);   // sin(pi*v)
    const float c1 = __builtin_amdgcn_cosf(0.5f * v);   // cos(pi*v)
    const float4* F = (const float4*)fin;

    float4 f0 = F[0], f1 = F[1];
    float den = f0.x, num = f0.y;
    den = fmaf(c1, f1.x, den);  den = fmaf(s1, f1.y, den);
    num = fmaf(c1, f1.z, num);  num = fmaf(s1, f1.w, num);

    const float tc = c1 + c1;
    float cm2 = 1.f, sm2 = 0.f, cm1 = c1, sm1 = s1;
    #pragma unroll
    for (int m = 2; m <= M; ++m) {        // Chebyshev recurrence in xp only
        float cn = fmaf(tc, cm1, -cm2);
        float sn = fmaf(tc, sm1, -sm2);
        cm2 = cm1; cm1 = cn; sm2 = sm1; sm1 = sn;
        float4 f = F[m];                  // ds_read_b128 broadcast
        den = fmaf(cn, f.x, den);  den = fmaf(sn, f.y, den);
        num = fmaf(cn, f.z, num);  num = fmaf(sn, f.w, num);
    }
    out[s * NPIX + p] = num / den;
}

extern "C" void kernel_launch(void* const* d_in, const int* in_sizes, int n_in,
                              void* d_out, int out_size, void* d_ws, size_t ws_size,
                              hipStream_t stream) {
    const float* x = (const float*)d_in[0];
    float* out = (float*)d_out;
    float* ws  = (float*)d_ws;            // 6*21*4 floats = 2016 B used
    moments_kernel<<<dim3(M, NSLICE), dim3(256), 0, stream>>>(x, ws);
    recombine_kernel<<<dim3(NPIX / 512, NSLICE), dim3(512), 0, stream>>>(x, ws, out);
}